// Round 1
// baseline (87.634 us; speedup 1.0000x reference)
//
#include <hip/hip_runtime.h>

// Gated pair-bias attention (AlphaFold-style), MI355X gfx950.
// B=8 S=1024 D=256 H=8 DH=32. All GEMM-shaped work in bf16 MFMA 16x16x32.
//
// Pipeline:
//   proj_kernel   : qh=(q Wq^T)*norm, sig=sigmoid(q Wg^T + bg), kh=k Wk^T, vh=v Wv^T   (bf16 in ws)
//   attn_kernel   : flash attention with additive mask + pair bias; og = sigmoid(g)*O  (bf16 in ws)
//   outproj_kernel: out = og Wo^T  (fp32 to d_out)

typedef __attribute__((ext_vector_type(4))) float f32x4;
typedef __attribute__((ext_vector_type(8))) unsigned short u16x8;
typedef __attribute__((ext_vector_type(8))) __bf16 bf16x8;

#define BB 8
#define SS 1024
#define DD 256
#define HH 8
#define DHD 32

__device__ __forceinline__ unsigned short f2b(float f) {
  unsigned u = __builtin_bit_cast(unsigned, f);
  u += 0x7fffu + ((u >> 16) & 1u);          // round-to-nearest-even
  return (unsigned short)(u >> 16);
}
__device__ __forceinline__ float b2f(unsigned short s) {
  unsigned u = ((unsigned)s) << 16;
  return __builtin_bit_cast(float, u);
}
__device__ __forceinline__ f32x4 mfma16(u16x8 a, u16x8 b, f32x4 c) {
  return __builtin_amdgcn_mfma_f32_16x16x32_bf16(
      __builtin_bit_cast(bf16x8, a), __builtin_bit_cast(bf16x8, b), c, 0, 0, 0);
}

// ---------------------------------------------------------------------------
// Projections: C[8192,256] = A[8192,256] * W[256,256]^T  (einsum bsd,ed->bse)
// grid (128 row-tiles, 4 col-tiles, 4 slots), 256 threads (4 waves).
// Tile 64x64, K-step 32. LDS chunks (16B) XOR-swizzled: chunk ^= (row>>1)&3.
// ---------------------------------------------------------------------------
__global__ __launch_bounds__(256) void proj_kernel(
    const float* __restrict__ q, const float* __restrict__ k,
    const float* __restrict__ v,
    const float* __restrict__ Wq, const float* __restrict__ Wg,
    const float* __restrict__ Wk, const float* __restrict__ Wv,
    const float* __restrict__ bg,
    unsigned short* __restrict__ qh, unsigned short* __restrict__ kh,
    unsigned short* __restrict__ vh, unsigned short* __restrict__ sig) {
  const int slot = blockIdx.z;
  const float* A = (slot <= 1) ? q : (slot == 2 ? k : v);
  const float* W = (slot == 0) ? Wq : (slot == 1 ? Wg : (slot == 2 ? Wk : Wv));
  const int row0 = blockIdx.x * 64, col0 = blockIdx.y * 64;
  const int tid = threadIdx.x;
  const int w = tid >> 6, lane = tid & 63, g = lane >> 4, c = lane & 15;
  const int sr = tid >> 2, sc = tid & 3;   // staging: row 0..63, chunk 0..3

  __shared__ alignas(16) unsigned short As[64 * 32];
  __shared__ alignas(16) unsigned short Ws[64 * 32];

  const f32x4 zero = {0.f, 0.f, 0.f, 0.f};
  f32x4 acc[4] = {zero, zero, zero, zero};

  for (int kk = 0; kk < 8; ++kk) {
    __syncthreads();
    {
      const float* ap = A + (size_t)(row0 + sr) * DD + kk * 32 + sc * 8;
      f32x4 f0 = *(const f32x4*)ap;
      f32x4 f1 = *(const f32x4*)(ap + 4);
      u16x8 a8;
#pragma unroll
      for (int j = 0; j < 4; ++j) { a8[j] = f2b(f0[j]); a8[j + 4] = f2b(f1[j]); }
      ((u16x8*)As)[sr * 4 + (sc ^ ((sr >> 1) & 3))] = a8;

      const float* wp = W + (size_t)(col0 + sr) * DD + kk * 32 + sc * 8;
      f32x4 w0 = *(const f32x4*)wp;
      f32x4 w1 = *(const f32x4*)(wp + 4);
      u16x8 w8;
#pragma unroll
      for (int j = 0; j < 4; ++j) { w8[j] = f2b(w0[j]); w8[j + 4] = f2b(w1[j]); }
      ((u16x8*)Ws)[sr * 4 + (sc ^ ((sr >> 1) & 3))] = w8;
    }
    __syncthreads();
    const int arow = 16 * w + c;
    u16x8 af = ((u16x8*)As)[arow * 4 + (g ^ ((arow >> 1) & 3))];
#pragma unroll
    for (int n = 0; n < 4; ++n) {
      const int brow = 16 * n + c;
      u16x8 wf = ((u16x8*)Ws)[brow * 4 + (g ^ ((brow >> 1) & 3))];
      acc[n] = mfma16(af, wf, acc[n]);
    }
  }

  // D layout: row = 4*(lane>>4)+r, col = lane&15 (m89-verified)
#pragma unroll
  for (int n = 0; n < 4; ++n) {
#pragma unroll
    for (int r = 0; r < 4; ++r) {
      const int row = row0 + 16 * w + 4 * g + r;
      const int col = col0 + 16 * n + c;
      const size_t idx = (size_t)row * DD + col;
      const float val = acc[n][r];
      if (slot == 0)      qh[idx] = f2b(val * 0.17677669529663687f);  // DH^-0.5
      else if (slot == 1) sig[idx] = f2b(1.0f / (1.0f + __expf(-(val + bg[col]))));
      else if (slot == 2) kh[idx] = f2b(val);
      else                vh[idx] = f2b(val);
    }
  }
}

// ---------------------------------------------------------------------------
// Flash attention. grid (16 q-tiles, H, B), 256 threads = 4 waves.
// Wave w owns q rows [qt*64 + 16w, +16). K-tile = 64 kv positions.
// ---------------------------------------------------------------------------
__global__ __launch_bounds__(256) void attn_kernel(
    const unsigned short* __restrict__ qh, const unsigned short* __restrict__ kh,
    const unsigned short* __restrict__ vh, const unsigned short* __restrict__ sig,
    const float* __restrict__ mask, const float* __restrict__ bias,
    unsigned short* __restrict__ og) {
  const int qt = blockIdx.x, h = blockIdx.y, b = blockIdx.z;
  const int tid = threadIdx.x;
  const int w = tid >> 6, lane = tid & 63, g = lane >> 4, c = lane & 15;
  const int sr = tid >> 2, sc = tid & 3;

  __shared__ alignas(16) unsigned short Ks[64 * 32];      // [kv][dh], swizzled
  __shared__ alignas(16) unsigned short Vt[32 * 64];      // [dh][kv], swizzled
  __shared__ alignas(16) unsigned short Ps[4][16 * 64];   // per-wave P tile

  // Q fragment straight from global: A[row=c][k=8g+i], DH=32 == MFMA K.
  const int qrow = b * SS + qt * 64 + w * 16 + c;
  const u16x8 qf = *(const u16x8*)(qh + (size_t)qrow * DD + h * DHD + g * 8);

  const f32x4 zero = {0.f, 0.f, 0.f, 0.f};
  f32x4 acc[2] = {zero, zero};                 // O accum: dh-tiles 0,1
  float m_r[4] = {-1e30f, -1e30f, -1e30f, -1e30f};
  float l_r[4] = {0.f, 0.f, 0.f, 0.f};

  const float* maskb = mask + b * SS;
  const float* biasb = bias + ((size_t)(h * SS + qt * 64 + w * 16)) * SS;

  for (int kt = 0; kt < 16; ++kt) {
    __syncthreads();  // guard restage vs previous PV reads
    {
      const unsigned short* kp =
          kh + (size_t)(b * SS + kt * 64 + sr) * DD + h * DHD + sc * 8;
      ((u16x8*)Ks)[sr * 4 + (sc ^ ((sr >> 1) & 3))] = *(const u16x8*)kp;

      const unsigned short* vp =
          vh + (size_t)(b * SS + kt * 64 + sr) * DD + h * DHD + sc * 8;
      u16x8 vv = *(const u16x8*)vp;
#pragma unroll
      for (int j = 0; j < 8; ++j) {     // transpose V into Vt[dh][kv]
        const int dh = sc * 8 + j;
        Vt[dh * 64 + (((sr >> 3) ^ (dh & 7)) << 3) + (sr & 7)] = vv[j];
      }
    }
    __syncthreads();

    // S = Q K^T : 4 MFMAs over kv sub-tiles of 16
    f32x4 sv[4];
#pragma unroll
    for (int t = 0; t < 4; ++t) {
      const int krow = 16 * t + c;
      u16x8 kf = ((u16x8*)Ks)[krow * 4 + (g ^ ((krow >> 1) & 3))];
      sv[t] = mfma16(qf, kf, zero);
    }
    // + mask + pair bias (lane holds S[q=4g+r][kv=16t+c])
#pragma unroll
    for (int t = 0; t < 4; ++t) {
      const float mk = maskb[kt * 64 + 16 * t + c];
#pragma unroll
      for (int r = 0; r < 4; ++r)
        sv[t][r] += mk + biasb[(size_t)(4 * g + r) * SS + kt * 64 + 16 * t + c];
    }
    // online softmax per q-row (16-lane butterfly within group g)
#pragma unroll
    for (int r = 0; r < 4; ++r) {
      float mx = fmaxf(fmaxf(sv[0][r], sv[1][r]), fmaxf(sv[2][r], sv[3][r]));
#pragma unroll
      for (int off = 1; off < 16; off <<= 1) mx = fmaxf(mx, __shfl_xor(mx, off));
      const float mnew = fmaxf(m_r[r], mx);
      const float scale = __expf(m_r[r] - mnew);
      float ps = 0.f;
#pragma unroll
      for (int t = 0; t < 4; ++t) {
        const float p = __expf(sv[t][r] - mnew);
        sv[t][r] = p;
        ps += p;
      }
#pragma unroll
      for (int off = 1; off < 16; off <<= 1) ps += __shfl_xor(ps, off);
      l_r[r] = l_r[r] * scale + ps;
      m_r[r] = mnew;
      acc[0][r] *= scale;
      acc[1][r] *= scale;
    }
    // P -> per-wave LDS (layout change D->A)
    unsigned short* P = Ps[w];
#pragma unroll
    for (int r = 0; r < 4; ++r) {
      const int qq = 4 * g + r;
#pragma unroll
      for (int t = 0; t < 4; ++t) {
        const int kv = 16 * t + c;
        P[qq * 64 + (((kv >> 3) ^ (qq & 7)) << 3) + (kv & 7)] = f2b(sv[t][r]);
      }
    }
    __syncthreads();
    // O += P V : contraction kv split in 2, dh-tiles of 16
#pragma unroll
    for (int s2 = 0; s2 < 2; ++s2) {
      u16x8 pf = ((u16x8*)P)[c * 8 + ((4 * s2 + g) ^ (c & 7))];
#pragma unroll
      for (int dt = 0; dt < 2; ++dt) {
        const int vrow = 16 * dt + c;
        u16x8 vf = ((u16x8*)Vt)[vrow * 8 + ((4 * s2 + g) ^ (vrow & 7))];
        acc[dt] = mfma16(pf, vf, acc[dt]);
      }
    }
  }

  // epilogue: normalize, gate with sigmoid(g), store bf16
#pragma unroll
  for (int r = 0; r < 4; ++r) {
    const float inv = 1.0f / l_r[r];
    const int row = b * SS + qt * 64 + w * 16 + 4 * g + r;
#pragma unroll
    for (int dt = 0; dt < 2; ++dt) {
      const int col = h * DHD + 16 * dt + c;
      const size_t idx = (size_t)row * DD + col;
      og[idx] = f2b(acc[dt][r] * inv * b2f(sig[idx]));
    }
  }
}

// ---------------------------------------------------------------------------
// Output projection: out[8192,256] = og[8192,256] * Wo[256,256]^T (fp32 out)
// ---------------------------------------------------------------------------
__global__ __launch_bounds__(256) void outproj_kernel(
    const unsigned short* __restrict__ og, const float* __restrict__ Wo,
    float* __restrict__ out) {
  const int row0 = blockIdx.x * 64, col0 = blockIdx.y * 64;
  const int tid = threadIdx.x;
  const int w = tid >> 6, lane = tid & 63, g = lane >> 4, c = lane & 15;
  const int sr = tid >> 2, sc = tid & 3;

  __shared__ alignas(16) unsigned short As[64 * 32];
  __shared__ alignas(16) unsigned short Ws[64 * 32];

  const f32x4 zero = {0.f, 0.f, 0.f, 0.f};
  f32x4 acc[4] = {zero, zero, zero, zero};

  for (int kk = 0; kk < 8; ++kk) {
    __syncthreads();
    {
      const unsigned short* ap = og + (size_t)(row0 + sr) * DD + kk * 32 + sc * 8;
      ((u16x8*)As)[sr * 4 + (sc ^ ((sr >> 1) & 3))] = *(const u16x8*)ap;

      const float* wp = Wo + (size_t)(col0 + sr) * DD + kk * 32 + sc * 8;
      f32x4 w0 = *(const f32x4*)wp;
      f32x4 w1 = *(const f32x4*)(wp + 4);
      u16x8 w8;
#pragma unroll
      for (int j = 0; j < 4; ++j) { w8[j] = f2b(w0[j]); w8[j + 4] = f2b(w1[j]); }
      ((u16x8*)Ws)[sr * 4 + (sc ^ ((sr >> 1) & 3))] = w8;
    }
    __syncthreads();
    const int arow = 16 * w + c;
    u16x8 af = ((u16x8*)As)[arow * 4 + (g ^ ((arow >> 1) & 3))];
#pragma unroll
    for (int n = 0; n < 4; ++n) {
      const int brow = 16 * n + c;
      u16x8 wf = ((u16x8*)Ws)[brow * 4 + (g ^ ((brow >> 1) & 3))];
      acc[n] = mfma16(af, wf, acc[n]);
    }
  }

#pragma unroll
  for (int n = 0; n < 4; ++n) {
#pragma unroll
    for (int r = 0; r < 4; ++r) {
      const int row = row0 + 16 * w + 4 * g + r;
      const int col = col0 + 16 * n + c;
      out[(size_t)row * DD + col] = acc[n][r];
    }
  }
}

extern "C" void kernel_launch(void* const* d_in, const int* in_sizes, int n_in,
                              void* d_out, int out_size, void* d_ws,
                              size_t ws_size, hipStream_t stream) {
  const float* q    = (const float*)d_in[0];
  const float* k    = (const float*)d_in[1];
  const float* v    = (const float*)d_in[2];
  const float* mask = (const float*)d_in[3];
  const float* bias = (const float*)d_in[4];
  const float* Wq   = (const float*)d_in[5];
  const float* Wk   = (const float*)d_in[6];
  const float* Wv   = (const float*)d_in[7];
  const float* Wg   = (const float*)d_in[8];
  const float* bg   = (const float*)d_in[9];
  const float* Wo   = (const float*)d_in[10];
  float* out = (float*)d_out;

  char* ws = (char*)d_ws;
  unsigned short* qh  = (unsigned short*)(ws);               // 4 MB bf16
  unsigned short* kh  = (unsigned short*)(ws + (4u << 20));  // 4 MB
  unsigned short* vh  = (unsigned short*)(ws + (8u << 20));  // 4 MB
  unsigned short* sig = (unsigned short*)(ws + (12u << 20)); // 4 MB
  unsigned short* og  = (unsigned short*)(ws + (16u << 20)); // 4 MB

  hipLaunchKernelGGL(proj_kernel, dim3(128, 4, 4), dim3(256), 0, stream,
                     q, k, v, Wq, Wg, Wk, Wv, bg, qh, kh, vh, sig);
  hipLaunchKernelGGL(attn_kernel, dim3(16, HH, BB), dim3(256), 0, stream,
                     qh, kh, vh, sig, mask, bias, og);
  hipLaunchKernelGGL(outproj_kernel, dim3(128, 4), dim3(256), 0, stream,
                     og, Wo, out);
}